// Round 8
// baseline (288.088 us; speedup 1.0000x reference)
//
#include <hip/hip_runtime.h>

// grid (1,4,1024,1024) f32 -> out (1,4,4096,4096) f32; cstart int32[2] in [0,512).
constexpr int C    = 4;
constexpr int GH   = 1024;
constexpr int GW   = 1024;
constexpr int HOUT = 4096;
constexpr int WOUT = 4096;

typedef float vfloat4 __attribute__((ext_vector_type(4)));

// R7 post-mortem: plain stores beat NT (write-combine, no RFO — proven by
// fillBuffer counters). Kernel ~57us = 284MB @ ~5.0 TB/s vs 6.5 TB/s fill
// ceiling. Residual theory: channel-fastest block order scatters concurrent
// blocks' 16 write streams across the whole 268MB (DRAM page thrash).
// This round: g-fastest block order — concurrent blocks write 4 contiguous
// row bands per channel. Arithmetic unchanged (absmax 1.525879e-05).

// 12-float window (three vfloat4 blocks); c unused on the 2-block path.
struct Win12 { vfloat4 a, b, c; };
template <int J> __device__ __forceinline__ float wget(const Win12& w) {
    static_assert(J >= 0 && J < 12, "window index");
    if constexpr (J < 4)      return w.a[J];
    else if constexpr (J < 8) return w.b[J - 4];
    else                      return w.c[J - 8];
}

// One output pixel; Q,I compile-time so all wget indices are constants.
// Window invariant: w[Q+I] == row[(mbase+I)&1023].
template <int Q, int I>
__device__ __forceinline__ float evalpix(const Win12& w0, const Win12& w1,
                                         int mbase, float wy) {
    constexpr float kInvOff = 1.0f / 511.5f;
    const int mx = (mbase + I) & (GW - 1);
    const float fx = ((float)mx - 511.5f) * kInvOff;
    float x = (fx + 1.0f) * 0.5f * (float)(GW - 1);
    x = fminf(fmaxf(x, 0.0f), (float)(GW - 1));
    const float x0f = floorf(x);
    const float wx  = x - x0f;
    const int   ix0 = (int)x0f;              // == mx or mx-1 (never <0: x>=0)

    const float wm1_0 = wget<Q + I - 1>(w0);
    const float wc_0  = wget<Q + I    >(w0);
    const float wp1_0 = wget<Q + I + 1>(w0);
    const float wm1_1 = wget<Q + I - 1>(w1);
    const float wc_1  = wget<Q + I    >(w1);
    const float wp1_1 = wget<Q + I + 1>(w1);

    const bool lo   = (ix0 != mx);           // floor rounded down to mx-1
    const bool edge = (mx == GW - 1);        // x1 clamp at right border

    const float v00 = lo ? wm1_0 : wc_0;
    const float v01 = lo ? wc_0 : (edge ? wc_0 : wp1_0);
    const float v10 = lo ? wm1_1 : wc_1;
    const float v11 = lo ? wc_1 : (edge ? wc_1 : wp1_1);

    const float top = v00 * (1.0f - wx) + v01 * wx;
    const float bot = v10 * (1.0f - wx) + v11 * wx;
    return top * (1.0f - wy) + bot * wy;
}

template <int Q>
__device__ __forceinline__ vfloat4 eval4(const Win12& w0, const Win12& w1,
                                         int mbase, float wy) {
    vfloat4 res;
    res[0] = evalpix<Q, 0>(w0, w1, mbase, wy);
    res[1] = evalpix<Q, 1>(w0, w1, mbase, wy);
    res[2] = evalpix<Q, 2>(w0, w1, mbase, wy);
    res[3] = evalpix<Q, 3>(w0, w1, mbase, wy);
    return res;
}

__global__ __launch_bounds__(256) void grid_sample_k(
    const float* __restrict__ grid,
    const int*   __restrict__ cstart,
    vfloat4*     __restrict__ out4)
{
    // 4096 blocks, g-fastest: concurrent blocks have consecutive grid rows,
    // so their writes form contiguous bands and their loads share rows in L2.
    const int g = blockIdx.x & 1023;        // grid row 0..1023
    const int c = blockIdx.x >> 10;         // channel 0..3

    const int sx = cstart[0];
    const int sy = cstart[1];

    const int oh0 = (g - sy) & (GH - 1);    // first output row for this g

    // y chain (verbatim; my == g)
    constexpr float kInvOff = 1.0f / 511.5f;
    const int my = g;
    const float fy = ((float)my - 511.5f) * kInvOff;
    float y = (fy + 1.0f) * 0.5f * (float)(GH - 1);
    y = fminf(fmaxf(y, 0.0f), (float)(GH - 1));
    const float y0f = floorf(y);
    const float wy  = y - y0f;
    const int   y0  = (int)y0f;
    const int   y1  = min(y0 + 1, GH - 1);

    const float* gp = grid + (size_t)c * (GH * GW);
    const vfloat4* __restrict__ row0 = (const vfloat4*)(gp + (size_t)y0 * GW);
    const vfloat4* __restrict__ row1 = (const vfloat4*)(gp + (size_t)y1 * GW);

    const int tid   = threadIdx.x;
    const int mbase = sx + (tid << 2);      // pre-mod grid col of px 0
    const int B     = (sx >> 2) + tid;      // aligned block index
    const int p     = sx & 3;               // uniform phase

    const int b0 = B & 255;
    const int b1 = (B + 1) & 255;

    vfloat4 res;
    if (p == 0) {
        // window reaches row[mx-1] -> needs block B-1 too (3 blocks)
        const int bm = (B + 255) & 255;
        Win12 w0, w1;
        w0.a = row0[bm]; w0.b = row0[b0]; w0.c = row0[b1];
        w1.a = row1[bm]; w1.b = row1[b0]; w1.c = row1[b1];
        res = eval4<4>(w0, w1, mbase, wy);
    } else {
        Win12 w0, w1;
        w0.a = row0[b0]; w0.b = row0[b1]; w0.c = w0.b;
        w1.a = row1[b0]; w1.b = row1[b1]; w1.c = w1.b;
        if (p == 1)      res = eval4<1>(w0, w1, mbase, wy);
        else if (p == 2) res = eval4<2>(w0, w1, mbase, wy);
        else             res = eval4<3>(w0, w1, mbase, wy);
    }

    // 16 replicated stores (4 row-repeats x 4 col-repeats), each
    // wave-coalesced; plain stores write-combine to full L2 lines.
    constexpr int ROW4 = WOUT / 4;          // 1024 vfloat4 per output row
#pragma unroll
    for (int rr = 0; rr < 4; ++rr) {
        const int oh = oh0 + (rr << 10);
        vfloat4* orow = out4 + ((size_t)c * HOUT + oh) * ROW4;
#pragma unroll
        for (int kc = 0; kc < 4; ++kc) {
            orow[(kc << 8) + tid] = res;
        }
    }
}

extern "C" void kernel_launch(void* const* d_in, const int* in_sizes, int n_in,
                              void* d_out, int out_size, void* d_ws, size_t ws_size,
                              hipStream_t stream)
{
    const float* grid   = (const float*)d_in[0];
    const int*   cstart = (const int*)d_in[1];
    vfloat4* out = (vfloat4*)d_out;

    const int nblk = C * GH;                // 4096 blocks, one per (c, grid row)
    grid_sample_k<<<nblk, 256, 0, stream>>>(grid, cstart, out);
}